// Round 13
// baseline (1922.060 us; speedup 1.0000x reference)
//
#include <hip/hip_runtime.h>
#include <hip/hip_bf16.h>
#include <cstdint>

#define T_DIM 4096
#define D_DIM 4096
#define I_DIM 12288
#define GRP   128

typedef __attribute__((ext_vector_type(8))) short bf16x8;   // MFMA A/B frag (8 bf16)
typedef __attribute__((ext_vector_type(4))) float f32x4;    // MFMA C/D frag
typedef __attribute__((ext_vector_type(4))) int   int32x4;

typedef __attribute__((address_space(3))) void lds_void;
typedef const __attribute__((address_space(1))) void gmem_void;

// f32 -> bf16 bits, round-to-nearest-even (finite inputs)
static __device__ __forceinline__ unsigned short f2bf(float f) {
    unsigned int u = __float_as_uint(f);
    u += 0x7FFFu + ((u >> 16) & 1u);
    return (unsigned short)(u >> 16);
}
static __device__ __forceinline__ float bf2f(unsigned short b) {
    return __uint_as_float(((unsigned int)b) << 16);
}

// ---------------- Hadamard (blockwise-128 FWHT), one wave per group, 2 elems/lane ----
__global__ void had_f32_to_bf16(const float* __restrict__ in, unsigned short* __restrict__ out,
                                int ngroups) {
    int gid = blockIdx.x * (blockDim.x >> 6) + (threadIdx.x >> 6);
    if (gid >= ngroups) return;
    int lane = threadIdx.x & 63;
    const float2 v2 = *reinterpret_cast<const float2*>(in + (size_t)gid * 128 + lane * 2);
    float v0 = v2.x, v1 = v2.y;
    { float t0 = v0 + v1, t1 = v0 - v1; v0 = t0; v1 = t1; }
#pragma unroll
    for (int m = 1; m <= 32; m <<= 1) {
        float b0 = __shfl_xor(v0, m);
        float b1 = __shfl_xor(v1, m);
        if (lane & m) { v0 = b0 - v0; v1 = b1 - v1; }
        else          { v0 = v0 + b0; v1 = v1 + b1; }
    }
    const float s = 0.08838834764831843f;  // 1/sqrt(128)
    unsigned int o = (unsigned int)f2bf(v0 * s) | ((unsigned int)f2bf(v1 * s) << 16);
    *reinterpret_cast<unsigned int*>(out + (size_t)gid * 128 + lane * 2) = o;
}

__global__ void had_bf16_inplace(unsigned short* __restrict__ buf, int ngroups) {
    int gid = blockIdx.x * (blockDim.x >> 6) + (threadIdx.x >> 6);
    if (gid >= ngroups) return;
    int lane = threadIdx.x & 63;
    unsigned int pv = *reinterpret_cast<const unsigned int*>(buf + (size_t)gid * 128 + lane * 2);
    float v0 = __uint_as_float((pv & 0xFFFFu) << 16);
    float v1 = __uint_as_float(pv & 0xFFFF0000u);
    { float t0 = v0 + v1, t1 = v0 - v1; v0 = t0; v1 = t1; }
#pragma unroll
    for (int m = 1; m <= 32; m <<= 1) {
        float b0 = __shfl_xor(v0, m);
        float b1 = __shfl_xor(v1, m);
        if (lane & m) { v0 = b0 - v0; v1 = b1 - v1; }
        else          { v0 = v0 + b0; v1 = v1 + b1; }
    }
    const float s = 0.08838834764831843f;
    unsigned int o = (unsigned int)f2bf(v0 * s) | ((unsigned int)f2bf(v1 * s) << 16);
    *reinterpret_cast<unsigned int*>(buf + (size_t)gid * 128 + lane * 2) = o;
}

// ---------------- weight dequant: int4-in-int32 [O,In] -> bf16 [O,In] ----------------
__global__ void dequant_w(const int* __restrict__ Wq, const float* __restrict__ S,
                          unsigned short* __restrict__ Wbf, int In, int total8) {
    int t = blockIdx.x * blockDim.x + threadIdx.x;
    if (t >= total8) return;
    size_t base = (size_t)t * 8;
    size_t row = base / (size_t)In;
    int col = (int)(base - row * (size_t)In);
    float sc = S[row * (size_t)(In >> 7) + (col >> 7)];
    const int32x4* p = reinterpret_cast<const int32x4*>(Wq + base);
    int32x4 a = p[0], b = p[1];
    float nsc = -8.0f * sc;
    unsigned int o0 = (unsigned int)f2bf((float)a.x * sc + nsc) |
                      ((unsigned int)f2bf((float)a.y * sc + nsc) << 16);
    unsigned int o1 = (unsigned int)f2bf((float)a.z * sc + nsc) |
                      ((unsigned int)f2bf((float)a.w * sc + nsc) << 16);
    unsigned int o2 = (unsigned int)f2bf((float)b.x * sc + nsc) |
                      ((unsigned int)f2bf((float)b.y * sc + nsc) << 16);
    unsigned int o3 = (unsigned int)f2bf((float)b.z * sc + nsc) |
                      ((unsigned int)f2bf((float)b.w * sc + nsc) << 16);
    *reinterpret_cast<uint4*>(Wbf + base) = make_uint4(o0, o1, o2, o3);
}

// =====================================================================================
// 128x128 GEMM, BK=32, 4 waves, 32KB LDS, ~120 VGPR -> 4 blocks/CU (16 waves/CU).
// m97-proven 2-barrier loop: stage(t+1)->buf^1 ; read frags buf ; 16 MFMA ; vmcnt(0) ;
// barrier. Cross-BLOCK phase offset overlaps LDS-pipe drain with matrix pipe (m114).
// C[M,N] = A[M,K] @ W[N,K]^T, bf16 in. MODE 0: bf16 out; 1: silu(C)*acc in place; 2: f32.
// Per wave 64x64 out = 4x4 frags of 16x16x32 (BK=32 = one MFMA-K). acc 64 regs.
// LDS: 2 buffers x (A 8KB | B 8KB) = 32KB. Buffer stride: 8192 shorts / 16384 bytes.
//   (r12 BUG was stride 16384 shorts -> buffer 1 out of bounds of the 32KB array.)
// Swizzle (row=64B=4 chunks): LDS chunk cl holds global chunk cl ^ ((r>>1)&3).
// Bank pattern on frag reads: 2-way (free, m136); DMA dests linear (rule #21).
// =====================================================================================

#define GBAR()  __builtin_amdgcn_s_barrier()
#define VMW0()  asm volatile("s_waitcnt vmcnt(0)" ::: "memory")

// stage one matrix half (A or B) of tile at k-base kb into buffer bb.
// 2 global_load_lds per thread; instr (wid*2+l) covers rows [(wid*2+l)*16, +16).
// matoff in SHORTS (0 for A, 4096 for B). Buffer stride 8192 shorts = 16KB.
#define STG128(src, row0, bb, matoff, kb)                                              \
  { _Pragma("unroll")                                                                  \
    for (int l_ = 0; l_ < 2; ++l_) {                                                   \
      const int r_ = (wid * 2 + l_) * 16 + (lane >> 2);                                \
      const int cg_ = (lane & 3) ^ ((r_ >> 1) & 3);                                    \
      const unsigned short* gp_ = (src) + (size_t)((row0) + r_) * K + (kb) + cg_ * 8;  \
      unsigned short* lp_ = lds + (bb) * 8192 + (matoff) + (wid * 2 + l_) * 512;       \
      __builtin_amdgcn_global_load_lds((gmem_void*)gp_, (lds_void*)lp_, 16, 0, 0);     \
    } }

// read A frags (4 m x K=32) of buffer bb; buffer stride 16384 BYTES
#define LDA128(bb)                                                                     \
  _Pragma("unroll")                                                                    \
  for (int mi_ = 0; mi_ < 4; ++mi_) {                                                  \
    int r_ = wr * 64 + mi_ * 16 + (lane & 15);                                         \
    af[mi_] = *reinterpret_cast<const bf16x8*>((const char*)lds + (bb) * 16384         \
              + r_ * 64 + ((kc ^ ((r_ >> 1) & 3)) << 4));                              \
  }

// read B frags (4 n x K=32) of buffer bb; B half at +8192 bytes
#define LDB128(bb)                                                                     \
  _Pragma("unroll")                                                                    \
  for (int ni_ = 0; ni_ < 4; ++ni_) {                                                  \
    int r_ = wc * 64 + ni_ * 16 + (lane & 15);                                         \
    bf[ni_] = *reinterpret_cast<const bf16x8*>((const char*)lds + (bb) * 16384 + 8192  \
              + r_ * 64 + ((kc ^ ((r_ >> 1) & 3)) << 4));                              \
  }

#define MF16X()                                                                        \
  _Pragma("unroll")                                                                    \
  for (int mi_ = 0; mi_ < 4; ++mi_)                                                    \
  _Pragma("unroll")                                                                    \
  for (int ni_ = 0; ni_ < 4; ++ni_)                                                    \
    acc[mi_][ni_] = __builtin_amdgcn_mfma_f32_16x16x32_bf16(                           \
        af[mi_], bf[ni_], acc[mi_][ni_], 0, 0, 0);

template<int MODE>
__global__ __launch_bounds__(256, 4)
void gemm128(const unsigned short* __restrict__ A,      // [M,K] bf16
             const unsigned short* __restrict__ W,      // [N,K] bf16
             void* __restrict__ C, int M, int N, int K)
{
    __shared__ __align__(16) unsigned short lds[16384];  // 32 KB: 2 x (A 8KB | B 8KB)

    const int MT = M >> 7;
    const int nwg = gridDim.x;
    const int bid = blockIdx.x;
    const int cpx = nwg >> 3;                     // nwg % 8 == 0 in all our launches
    const int wg  = (bid & 7) * cpx + (bid >> 3); // bijective XCD swizzle
    const int m0 = (wg % MT) << 7;
    const int n0 = (wg / MT) << 7;

    const int tid  = threadIdx.x;
    const int lane = tid & 63;
    const int wid  = tid >> 6;                    // 0..3
    const int wr = wid >> 1;                      // 0..1 (M half)
    const int wc = wid & 1;                       // 0..1 (N half)
    const int kc = lane >> 4;                     // 16B k-chunk selector (0..3)

    f32x4 acc[4][4];
#pragma unroll
    for (int i = 0; i < 4; ++i)
#pragma unroll
        for (int j = 0; j < 4; ++j) acc[i][j] = (f32x4)0.0f;

    const int NT = K >> 5;                        // K-tiles of 32 (128 or 384)

    bf16x8 af[4], bf[4];

    // ---- prologue: stage tile 0 into buf 0 ----
    STG128(A, m0, 0, 0, 0);
    STG128(W, n0, 0, 4096, 0);
    VMW0();
    GBAR();

    for (int t = 0; t < NT; ++t) {
        const int bb = t & 1;
        // stage next tile into the other buffer (its reads completed last iteration)
        if (t + 1 < NT) {
            const int kn = (t + 1) << 5;
            STG128(A, m0, bb ^ 1, 0, kn);
            STG128(W, n0, bb ^ 1, 4096, kn);
        }
        // read this tile's frags; compiler interleaves lgkm waits with MFMAs
        LDA128(bb); LDB128(bb);
        MF16X();
        VMW0();                                   // next tile's stage landed
        GBAR();                                   // all waves done reading bb
    }

    // ---- epilogue: D-frag col=lane&15, row=(lane>>4)*4+r ----
#pragma unroll
    for (int mi = 0; mi < 4; ++mi)
#pragma unroll
        for (int ni = 0; ni < 4; ++ni) {
            const int col = n0 + wc * 64 + ni * 16 + (lane & 15);
#pragma unroll
            for (int r = 0; r < 4; ++r) {
                const int row = m0 + wr * 64 + mi * 16 + ((lane >> 4) << 2) + r;
                const size_t idx = (size_t)row * N + col;
                if (MODE == 2) {
                    ((float*)C)[idx] = acc[mi][ni][r];
                } else if (MODE == 0) {
                    ((unsigned short*)C)[idx] = f2bf(acc[mi][ni][r]);
                } else {
                    float g = bf2f(((unsigned short*)C)[idx]);
                    float u = acc[mi][ni][r];
                    float h = (g / (1.0f + __expf(-g))) * u;
                    ((unsigned short*)C)[idx] = f2bf(h);
                }
            }
        }
}

// ================== FALLBACK (round-1 verified): in-loop dequant GEMMs ==============
__global__ __launch_bounds__(256, 2)
void gemm_gateup_fb(const unsigned short* __restrict__ Xr,
                    const int* __restrict__ Wg, const float* __restrict__ Sg,
                    const int* __restrict__ Wu, const float* __restrict__ Su,
                    unsigned short* __restrict__ H)
{
    __shared__ __align__(16) unsigned short lA [128 * 64];
    __shared__ __align__(16) unsigned short lBg[128 * 64];
    __shared__ __align__(16) unsigned short lBu[128 * 64];
    const int MT = T_DIM / 128;
    const int bid = blockIdx.x;
    const int m0 = (bid % MT) * 128;
    const int n0 = (bid / MT) * 128;
    const int tid  = threadIdx.x;
    const int lane = tid & 63;
    const int wid  = tid >> 6;
    const int wr = wid >> 1, wc = wid & 1;
    f32x4 accG[4][4], accU[4][4];
#pragma unroll
    for (int i = 0; i < 4; ++i)
#pragma unroll
        for (int j = 0; j < 4; ++j) { accG[i][j] = (f32x4)0.0f; accU[i][j] = (f32x4)0.0f; }
    const int arow = lane >> 3;
    const int acol = (lane & 7) * 8;
    const int SStride = D_DIM / GRP;
    for (int k0 = 0; k0 < D_DIM; k0 += 64) {
        __syncthreads();
#pragma unroll
        for (int it = 0; it < 4; ++it) {
            int chunk = wid * 4 + it;
            const unsigned short* gp = Xr + (size_t)(m0 + chunk * 8 + arow) * D_DIM + k0 + acol;
            __builtin_amdgcn_global_load_lds((gmem_void*)gp, (lds_void*)(lA + chunk * 512), 16, 0, 0);
        }
        const int g = k0 >> 7;
#pragma unroll
        for (int i = 0; i < 8; ++i) {
            int linear = i * 1024 + tid * 4;
            int r = linear >> 6;
            int c = linear & 63;
            const int32x4 wg = *reinterpret_cast<const int32x4*>(Wg + (size_t)(n0 + r) * D_DIM + k0 + c);
            const int32x4 wu = *reinterpret_cast<const int32x4*>(Wu + (size_t)(n0 + r) * D_DIM + k0 + c);
            float scg = Sg[(size_t)(n0 + r) * SStride + g];
            float scu = Su[(size_t)(n0 + r) * SStride + g];
            unsigned int g01 = (unsigned int)f2bf((float)(wg.x - 8) * scg) | ((unsigned int)f2bf((float)(wg.y - 8) * scg) << 16);
            unsigned int g23 = (unsigned int)f2bf((float)(wg.z - 8) * scg) | ((unsigned int)f2bf((float)(wg.w - 8) * scg) << 16);
            unsigned int u01 = (unsigned int)f2bf((float)(wu.x - 8) * scu) | ((unsigned int)f2bf((float)(wu.y - 8) * scu) << 16);
            unsigned int u23 = (unsigned int)f2bf((float)(wu.z - 8) * scu) | ((unsigned int)f2bf((float)(wu.w - 8) * scu) << 16);
            *reinterpret_cast<uint2*>(lBg + r * 64 + c) = make_uint2(g01, g23);
            *reinterpret_cast<uint2*>(lBu + r * 64 + c) = make_uint2(u01, u23);
        }
        __syncthreads();
#pragma unroll
        for (int ks = 0; ks < 2; ++ks) {
            const int koff = ks * 32 + (lane >> 4) * 8;
            bf16x8 af[4], bg[4], bu[4];
#pragma unroll
            for (int mi = 0; mi < 4; ++mi)
                af[mi] = *reinterpret_cast<const bf16x8*>(lA + (wr * 64 + mi * 16 + (lane & 15)) * 64 + koff);
#pragma unroll
            for (int ni = 0; ni < 4; ++ni) {
                bg[ni] = *reinterpret_cast<const bf16x8*>(lBg + (wc * 64 + ni * 16 + (lane & 15)) * 64 + koff);
                bu[ni] = *reinterpret_cast<const bf16x8*>(lBu + (wc * 64 + ni * 16 + (lane & 15)) * 64 + koff);
            }
#pragma unroll
            for (int mi = 0; mi < 4; ++mi)
#pragma unroll
                for (int ni = 0; ni < 4; ++ni) {
                    accG[mi][ni] = __builtin_amdgcn_mfma_f32_16x16x32_bf16(af[mi], bg[ni], accG[mi][ni], 0, 0, 0);
                    accU[mi][ni] = __builtin_amdgcn_mfma_f32_16x16x32_bf16(af[mi], bu[ni], accU[mi][ni], 0, 0, 0);
                }
        }
    }
#pragma unroll
    for (int mi = 0; mi < 4; ++mi)
#pragma unroll
        for (int ni = 0; ni < 4; ++ni) {
            const int col = n0 + wc * 64 + ni * 16 + (lane & 15);
#pragma unroll
            for (int r = 0; r < 4; ++r) {
                const int row = m0 + wr * 64 + mi * 16 + (lane >> 4) * 4 + r;
                float gv = accG[mi][ni][r];
                float uv = accU[mi][ni][r];
                float hv = (gv / (1.0f + __expf(-gv))) * uv;
                H[(size_t)row * I_DIM + col] = f2bf(hv);
            }
        }
}

__global__ __launch_bounds__(256, 2)
void gemm_down_fb(const unsigned short* __restrict__ Hr,
                  const int* __restrict__ Wd, const float* __restrict__ Sd,
                  float* __restrict__ Out)
{
    __shared__ __align__(16) unsigned short lA[128 * 64];
    __shared__ __align__(16) unsigned short lB[128 * 64];
    const int MT = T_DIM / 128;
    const int bid = blockIdx.x;
    const int m0 = (bid % MT) * 128;
    const int n0 = (bid / MT) * 128;
    const int tid  = threadIdx.x;
    const int lane = tid & 63;
    const int wid  = tid >> 6;
    const int wr = wid >> 1, wc = wid & 1;
    f32x4 acc[4][4];
#pragma unroll
    for (int i = 0; i < 4; ++i)
#pragma unroll
        for (int j = 0; j < 4; ++j) acc[i][j] = (f32x4)0.0f;
    const int arow = lane >> 3;
    const int acol = (lane & 7) * 8;
    const int SStride = I_DIM / GRP;
    for (int k0 = 0; k0 < I_DIM; k0 += 64) {
        __syncthreads();
#pragma unroll
        for (int it = 0; it < 4; ++it) {
            int chunk = wid * 4 + it;
            const unsigned short* gp = Hr + (size_t)(m0 + chunk * 8 + arow) * I_DIM + k0 + acol;
            __builtin_amdgcn_global_load_lds((gmem_void*)gp, (lds_void*)(lA + chunk * 512), 16, 0, 0);
        }
        const int g = k0 >> 7;
#pragma unroll
        for (int i = 0; i < 8; ++i) {
            int linear = i * 1024 + tid * 4;
            int r = linear >> 6;
            int c = linear & 63;
            const int32x4 wd = *reinterpret_cast<const int32x4*>(Wd + (size_t)(n0 + r) * I_DIM + k0 + c);
            float sc = Sd[(size_t)(n0 + r) * SStride + g];
            unsigned int d01 = (unsigned int)f2bf((float)(wd.x - 8) * sc) | ((unsigned int)f2bf((float)(wd.y - 8) * sc) << 16);
            unsigned int d23 = (unsigned int)f2bf((float)(wd.z - 8) * sc) | ((unsigned int)f2bf((float)(wd.w - 8) * sc) << 16);
            *reinterpret_cast<uint2*>(lB + r * 64 + c) = make_uint2(d01, d23);
        }
        __syncthreads();
#pragma unroll
        for (int ks = 0; ks < 2; ++ks) {
            const int koff = ks * 32 + (lane >> 4) * 8;
            bf16x8 af[4], bfr[4];
#pragma unroll
            for (int mi = 0; mi < 4; ++mi)
                af[mi] = *reinterpret_cast<const bf16x8*>(lA + (wr * 64 + mi * 16 + (lane & 15)) * 64 + koff);
#pragma unroll
            for (int ni = 0; ni < 4; ++ni)
                bfr[ni] = *reinterpret_cast<const bf16x8*>(lB + (wc * 64 + ni * 16 + (lane & 15)) * 64 + koff);
#pragma unroll
            for (int mi = 0; mi < 4; ++mi)
#pragma unroll
                for (int ni = 0; ni < 4; ++ni)
                    acc[mi][ni] = __builtin_amdgcn_mfma_f32_16x16x32_bf16(af[mi], bfr[ni], acc[mi][ni], 0, 0, 0);
        }
    }
#pragma unroll
    for (int mi = 0; mi < 4; ++mi)
#pragma unroll
        for (int ni = 0; ni < 4; ++ni) {
            const int col = n0 + wc * 64 + ni * 16 + (lane & 15);
#pragma unroll
            for (int r = 0; r < 4; ++r) {
                const int row = m0 + wr * 64 + mi * 16 + (lane >> 4) * 4 + r;
                Out[(size_t)row * D_DIM + col] = acc[mi][ni][r];
            }
        }
}

extern "C" void kernel_launch(void* const* d_in, const int* in_sizes, int n_in,
                              void* d_out, int out_size, void* d_ws, size_t ws_size,
                              hipStream_t stream) {
    const float* x       = (const float*)d_in[0];
    const int*   wq_gate = (const int*)d_in[1];
    const float* s_gate  = (const float*)d_in[2];
    const int*   wq_up   = (const int*)d_in[3];
    const float* s_up    = (const float*)d_in[4];
    const int*   wq_down = (const int*)d_in[5];
    const float* s_down  = (const float*)d_in[6];
    float* out = (float*)d_out;

    const size_t XR_E = (size_t)T_DIM * D_DIM;      // 16.8M
    const size_t H_E  = (size_t)T_DIM * I_DIM;      // 50.3M
    const size_t W_E  = (size_t)I_DIM * D_DIM;      // 50.3M
    const size_t need = (XR_E + H_E + 2 * W_E) * sizeof(unsigned short);  // 335.5 MB

    unsigned short* xr = (unsigned short*)d_ws;
    unsigned short* h  = xr + XR_E;

    // 1) xr = hadamard(x) -> bf16
    {
        int ngroups = (int)(XR_E / 128);
        had_f32_to_bf16<<<dim3(ngroups / 4), dim3(256), 0, stream>>>(x, xr, ngroups);
    }

    if (ws_size >= need) {
        unsigned short* wgbf = h + H_E;
        unsigned short* wubf = wgbf + W_E;
        int total8 = (int)(W_E / 8);
        // 2) pre-dequant gate & up weights -> bf16
        dequant_w<<<dim3((total8 + 255) / 256), dim3(256), 0, stream>>>(wq_gate, s_gate, wgbf, D_DIM, total8);
        dequant_w<<<dim3((total8 + 255) / 256), dim3(256), 0, stream>>>(wq_up,   s_up,   wubf, D_DIM, total8);
        // 3) gate = xr @ Wg^T  (bf16, into h)
        gemm128<0><<<dim3((T_DIM / 128) * (I_DIM / 128)), dim3(256), 0, stream>>>(
            xr, wgbf, (void*)h, T_DIM, I_DIM, D_DIM);
        // 4) h = silu(gate) * (xr @ Wu^T)   (fused epilogue, in place over h)
        gemm128<1><<<dim3((T_DIM / 128) * (I_DIM / 128)), dim3(256), 0, stream>>>(
            xr, wubf, (void*)h, T_DIM, I_DIM, D_DIM);
        // 5) h = hadamard(h) in place
        {
            int ngroups = (int)(H_E / 128);
            had_bf16_inplace<<<dim3(ngroups / 4), dim3(256), 0, stream>>>(h, ngroups);
        }
        // 6) dequant down weights (reuse gate buffer)
        dequant_w<<<dim3((total8 + 255) / 256), dim3(256), 0, stream>>>(wq_down, s_down, wgbf, I_DIM, total8);
        // 7) out = h @ Wd^T  (f32)
        gemm128<2><<<dim3((T_DIM / 128) * (D_DIM / 128)), dim3(256), 0, stream>>>(
            h, wgbf, (void*)out, T_DIM, D_DIM, I_DIM);
    } else {
        // fallback: round-1 verified path (in-loop dequant)
        gemm_gateup_fb<<<dim3((T_DIM / 128) * (I_DIM / 128)), dim3(256), 0, stream>>>(
            xr, wq_gate, s_gate, wq_up, s_up, h);
        {
            int ngroups = (int)(H_E / 128);
            had_bf16_inplace<<<dim3(ngroups / 4), dim3(256), 0, stream>>>(h, ngroups);
        }
        gemm_down_fb<<<dim3((T_DIM / 128) * (D_DIM / 128)), dim3(256), 0, stream>>>(
            h, wq_down, s_down, out);
    }
}

// Round 14
// 1535.920 us; speedup vs baseline: 1.2514x; 1.2514x over previous
//
#include <hip/hip_runtime.h>
#include <hip/hip_bf16.h>
#include <cstdint>

#define T_DIM 4096
#define D_DIM 4096
#define I_DIM 12288
#define GRP   128

typedef __attribute__((ext_vector_type(8))) short bf16x8;   // MFMA A/B frag (8 bf16)
typedef __attribute__((ext_vector_type(4))) float f32x4;    // MFMA C/D frag
typedef __attribute__((ext_vector_type(4))) int   int32x4;

typedef __attribute__((address_space(3))) void lds_void;
typedef const __attribute__((address_space(1))) void gmem_void;

// f32 -> bf16 bits, round-to-nearest-even (finite inputs)
static __device__ __forceinline__ unsigned short f2bf(float f) {
    unsigned int u = __float_as_uint(f);
    u += 0x7FFFu + ((u >> 16) & 1u);
    return (unsigned short)(u >> 16);
}
static __device__ __forceinline__ float bf2f(unsigned short b) {
    return __uint_as_float(((unsigned int)b) << 16);
}

// ---------------- Hadamard (blockwise-128 FWHT), one wave per group, 2 elems/lane ----
__global__ void had_f32_to_bf16(const float* __restrict__ in, unsigned short* __restrict__ out,
                                int ngroups) {
    int gid = blockIdx.x * (blockDim.x >> 6) + (threadIdx.x >> 6);
    if (gid >= ngroups) return;
    int lane = threadIdx.x & 63;
    const float2 v2 = *reinterpret_cast<const float2*>(in + (size_t)gid * 128 + lane * 2);
    float v0 = v2.x, v1 = v2.y;
    { float t0 = v0 + v1, t1 = v0 - v1; v0 = t0; v1 = t1; }
#pragma unroll
    for (int m = 1; m <= 32; m <<= 1) {
        float b0 = __shfl_xor(v0, m);
        float b1 = __shfl_xor(v1, m);
        if (lane & m) { v0 = b0 - v0; v1 = b1 - v1; }
        else          { v0 = v0 + b0; v1 = v1 + b1; }
    }
    const float s = 0.08838834764831843f;  // 1/sqrt(128)
    unsigned int o = (unsigned int)f2bf(v0 * s) | ((unsigned int)f2bf(v1 * s) << 16);
    *reinterpret_cast<unsigned int*>(out + (size_t)gid * 128 + lane * 2) = o;
}

__global__ void had_bf16_inplace(unsigned short* __restrict__ buf, int ngroups) {
    int gid = blockIdx.x * (blockDim.x >> 6) + (threadIdx.x >> 6);
    if (gid >= ngroups) return;
    int lane = threadIdx.x & 63;
    unsigned int pv = *reinterpret_cast<const unsigned int*>(buf + (size_t)gid * 128 + lane * 2);
    float v0 = __uint_as_float((pv & 0xFFFFu) << 16);
    float v1 = __uint_as_float(pv & 0xFFFF0000u);
    { float t0 = v0 + v1, t1 = v0 - v1; v0 = t0; v1 = t1; }
#pragma unroll
    for (int m = 1; m <= 32; m <<= 1) {
        float b0 = __shfl_xor(v0, m);
        float b1 = __shfl_xor(v1, m);
        if (lane & m) { v0 = b0 - v0; v1 = b1 - v1; }
        else          { v0 = v0 + b0; v1 = v1 + b1; }
    }
    const float s = 0.08838834764831843f;
    unsigned int o = (unsigned int)f2bf(v0 * s) | ((unsigned int)f2bf(v1 * s) << 16);
    *reinterpret_cast<unsigned int*>(buf + (size_t)gid * 128 + lane * 2) = o;
}

// ---------------- weight dequant: int4-in-int32 [O,In] -> bf16 [O,In] ----------------
__global__ void dequant_w(const int* __restrict__ Wq, const float* __restrict__ S,
                          unsigned short* __restrict__ Wbf, int In, int total8) {
    int t = blockIdx.x * blockDim.x + threadIdx.x;
    if (t >= total8) return;
    size_t base = (size_t)t * 8;
    size_t row = base / (size_t)In;
    int col = (int)(base - row * (size_t)In);
    float sc = S[row * (size_t)(In >> 7) + (col >> 7)];
    const int32x4* p = reinterpret_cast<const int32x4*>(Wq + base);
    int32x4 a = p[0], b = p[1];
    float nsc = -8.0f * sc;
    unsigned int o0 = (unsigned int)f2bf((float)a.x * sc + nsc) |
                      ((unsigned int)f2bf((float)a.y * sc + nsc) << 16);
    unsigned int o1 = (unsigned int)f2bf((float)a.z * sc + nsc) |
                      ((unsigned int)f2bf((float)a.w * sc + nsc) << 16);
    unsigned int o2 = (unsigned int)f2bf((float)b.x * sc + nsc) |
                      ((unsigned int)f2bf((float)b.y * sc + nsc) << 16);
    unsigned int o3 = (unsigned int)f2bf((float)b.z * sc + nsc) |
                      ((unsigned int)f2bf((float)b.w * sc + nsc) << 16);
    *reinterpret_cast<uint4*>(Wbf + base) = make_uint4(o0, o1, o2, o3);
}

// =====================================================================================
// 128(M) x 256(N) GEMM, BK=32, 8 waves (2m x 4n, per-wave 64x64, acc 64), 48KB LDS,
// __launch_bounds__(512,4) -> ~120 regs -> 2 blocks/CU (16 waves). Cross-block overlap
// (m114) + BN=256 keeps the streamed weight panel wide so A is re-passed only N/256
// times (r13's 128^2 was re-passed N/128 times -> 1.7GB fetch, HBM-bound).
// C[M,N] = A[M,K] @ W[N,K]^T, bf16 in. MODE 0: bf16 out; 1: silu(C)*acc in place; 2: f32.
// LDS: 2 buf x (A[128][32] 8KB | B[256][32] 16KB) = 48KB. Buffer stride 12288 shorts.
// Swizzle (row=64B=4 chunks): LDS chunk cl holds global chunk cl ^ ((r>>1)&3);
// read at chunk kc ^ ((r>>1)&3). Verified involution (r13 passed with it).
// =====================================================================================

#define GBAR()  __builtin_amdgcn_s_barrier()
#define VMW0()  asm volatile("s_waitcnt vmcnt(0)" ::: "memory")

// stage A half (128 rows): 1 instr/thread. Buffer stride 12288 shorts (24KB).
#define STGA(bb, kb)                                                                   \
  { const int r_ = (tid >> 2);                                                         \
    const int cg_ = (tid & 3) ^ ((r_ >> 1) & 3);                                       \
    const unsigned short* gp_ = A + (size_t)(m0 + r_) * K + (kb) + cg_ * 8;            \
    unsigned short* lp_ = lds + (bb) * 12288 + wid * 512;                              \
    __builtin_amdgcn_global_load_lds((gmem_void*)gp_, (lds_void*)lp_, 16, 0, 0); }

// stage B half (256 rows): 2 instr/thread. B at +4096 shorts within buffer.
#define STGB(bb, kb)                                                                   \
  { _Pragma("unroll")                                                                  \
    for (int l_ = 0; l_ < 2; ++l_) {                                                   \
      const int r_ = l_ * 128 + (tid >> 2);                                            \
      const int cg_ = (tid & 3) ^ ((r_ >> 1) & 3);                                     \
      const unsigned short* gp_ = W + (size_t)(n0 + r_) * K + (kb) + cg_ * 8;          \
      unsigned short* lp_ = lds + (bb) * 12288 + 4096 + l_ * 4096 + wid * 512;         \
      __builtin_amdgcn_global_load_lds((gmem_void*)gp_, (lds_void*)lp_, 16, 0, 0);     \
    } }

// read A frags (4 m x K=32) of buffer bb; buffer stride 24576 BYTES
#define LDA128(bb)                                                                     \
  _Pragma("unroll")                                                                    \
  for (int mi_ = 0; mi_ < 4; ++mi_) {                                                  \
    int r_ = wr * 64 + mi_ * 16 + (lane & 15);                                         \
    af[mi_] = *reinterpret_cast<const bf16x8*>((const char*)lds + (bb) * 24576         \
              + r_ * 64 + ((kc ^ ((r_ >> 1) & 3)) << 4));                              \
  }

// read B frags (4 n x K=32) of buffer bb; B half at +8192 bytes
#define LDB256(bb)                                                                     \
  _Pragma("unroll")                                                                    \
  for (int ni_ = 0; ni_ < 4; ++ni_) {                                                  \
    int r_ = wc * 64 + ni_ * 16 + (lane & 15);                                         \
    bf[ni_] = *reinterpret_cast<const bf16x8*>((const char*)lds + (bb) * 24576 + 8192  \
              + r_ * 64 + ((kc ^ ((r_ >> 1) & 3)) << 4));                              \
  }

#define MF16X()                                                                        \
  _Pragma("unroll")                                                                    \
  for (int mi_ = 0; mi_ < 4; ++mi_)                                                    \
  _Pragma("unroll")                                                                    \
  for (int ni_ = 0; ni_ < 4; ++ni_)                                                    \
    acc[mi_][ni_] = __builtin_amdgcn_mfma_f32_16x16x32_bf16(                           \
        af[mi_], bf[ni_], acc[mi_][ni_], 0, 0, 0);

template<int MODE>
__global__ __launch_bounds__(512, 4)
void gemm128x256(const unsigned short* __restrict__ A,  // [M,K] bf16
                 const unsigned short* __restrict__ W,  // [N,K] bf16
                 void* __restrict__ C, int M, int N, int K)
{
    __shared__ __align__(16) unsigned short lds[24576];  // 48 KB: 2 x (A 8KB | B 16KB)

    const int MT = M >> 7;                        // tiles along M (128-rows)
    const int nwg = gridDim.x;
    const int bid = blockIdx.x;
    const int cpx = nwg >> 3;                     // nwg % 8 == 0 in all our launches
    const int wg  = (bid & 7) * cpx + (bid >> 3); // bijective XCD swizzle
    const int m0 = (wg % MT) << 7;
    const int n0 = (wg / MT) << 8;

    const int tid  = threadIdx.x;
    const int lane = tid & 63;
    const int wid  = tid >> 6;                    // 0..7
    const int wr = wid >> 2;                      // 0..1 (M half)
    const int wc = wid & 3;                       // 0..3 (N quarter)
    const int kc = lane >> 4;                     // 16B k-chunk selector (0..3)

    f32x4 acc[4][4];
#pragma unroll
    for (int i = 0; i < 4; ++i)
#pragma unroll
        for (int j = 0; j < 4; ++j) acc[i][j] = (f32x4)0.0f;

    const int NT = K >> 5;                        // K-tiles of 32

    bf16x8 af[4], bf[4];

    // ---- prologue: stage tile 0 into buf 0 ----
    STGA(0, 0);
    STGB(0, 0);
    VMW0();
    GBAR();

    for (int t = 0; t < NT; ++t) {
        const int bb = t & 1;
        // stage next tile into the other buffer (its reads completed last iteration)
        if (t + 1 < NT) {
            const int kn = (t + 1) << 5;
            STGA(bb ^ 1, kn);
            STGB(bb ^ 1, kn);
        }
        // read this tile's frags; compiler interleaves lgkm waits with MFMAs
        LDA128(bb); LDB256(bb);
        MF16X();
        VMW0();                                   // next tile's stage landed
        GBAR();                                   // all waves done reading bb
    }

    // ---- epilogue: D-frag col=lane&15, row=(lane>>4)*4+r ----
#pragma unroll
    for (int mi = 0; mi < 4; ++mi)
#pragma unroll
        for (int ni = 0; ni < 4; ++ni) {
            const int col = n0 + wc * 64 + ni * 16 + (lane & 15);
#pragma unroll
            for (int r = 0; r < 4; ++r) {
                const int row = m0 + wr * 64 + mi * 16 + ((lane >> 4) << 2) + r;
                const size_t idx = (size_t)row * N + col;
                if (MODE == 2) {
                    ((float*)C)[idx] = acc[mi][ni][r];
                } else if (MODE == 0) {
                    ((unsigned short*)C)[idx] = f2bf(acc[mi][ni][r]);
                } else {
                    float g = bf2f(((unsigned short*)C)[idx]);
                    float u = acc[mi][ni][r];
                    float h = (g / (1.0f + __expf(-g))) * u;
                    ((unsigned short*)C)[idx] = f2bf(h);
                }
            }
        }
}

// ================== FALLBACK (round-1 verified): in-loop dequant GEMMs ==============
__global__ __launch_bounds__(256, 2)
void gemm_gateup_fb(const unsigned short* __restrict__ Xr,
                    const int* __restrict__ Wg, const float* __restrict__ Sg,
                    const int* __restrict__ Wu, const float* __restrict__ Su,
                    unsigned short* __restrict__ H)
{
    __shared__ __align__(16) unsigned short lA [128 * 64];
    __shared__ __align__(16) unsigned short lBg[128 * 64];
    __shared__ __align__(16) unsigned short lBu[128 * 64];
    const int MT = T_DIM / 128;
    const int bid = blockIdx.x;
    const int m0 = (bid % MT) * 128;
    const int n0 = (bid / MT) * 128;
    const int tid  = threadIdx.x;
    const int lane = tid & 63;
    const int wid  = tid >> 6;
    const int wr = wid >> 1, wc = wid & 1;
    f32x4 accG[4][4], accU[4][4];
#pragma unroll
    for (int i = 0; i < 4; ++i)
#pragma unroll
        for (int j = 0; j < 4; ++j) { accG[i][j] = (f32x4)0.0f; accU[i][j] = (f32x4)0.0f; }
    const int arow = lane >> 3;
    const int acol = (lane & 7) * 8;
    const int SStride = D_DIM / GRP;
    for (int k0 = 0; k0 < D_DIM; k0 += 64) {
        __syncthreads();
#pragma unroll
        for (int it = 0; it < 4; ++it) {
            int chunk = wid * 4 + it;
            const unsigned short* gp = Xr + (size_t)(m0 + chunk * 8 + arow) * D_DIM + k0 + acol;
            __builtin_amdgcn_global_load_lds((gmem_void*)gp, (lds_void*)(lA + chunk * 512), 16, 0, 0);
        }
        const int g = k0 >> 7;
#pragma unroll
        for (int i = 0; i < 8; ++i) {
            int linear = i * 1024 + tid * 4;
            int r = linear >> 6;
            int c = linear & 63;
            const int32x4 wg = *reinterpret_cast<const int32x4*>(Wg + (size_t)(n0 + r) * D_DIM + k0 + c);
            const int32x4 wu = *reinterpret_cast<const int32x4*>(Wu + (size_t)(n0 + r) * D_DIM + k0 + c);
            float scg = Sg[(size_t)(n0 + r) * SStride + g];
            float scu = Su[(size_t)(n0 + r) * SStride + g];
            unsigned int g01 = (unsigned int)f2bf((float)(wg.x - 8) * scg) | ((unsigned int)f2bf((float)(wg.y - 8) * scg) << 16);
            unsigned int g23 = (unsigned int)f2bf((float)(wg.z - 8) * scg) | ((unsigned int)f2bf((float)(wg.w - 8) * scg) << 16);
            unsigned int u01 = (unsigned int)f2bf((float)(wu.x - 8) * scu) | ((unsigned int)f2bf((float)(wu.y - 8) * scu) << 16);
            unsigned int u23 = (unsigned int)f2bf((float)(wu.z - 8) * scu) | ((unsigned int)f2bf((float)(wu.w - 8) * scu) << 16);
            *reinterpret_cast<uint2*>(lBg + r * 64 + c) = make_uint2(g01, g23);
            *reinterpret_cast<uint2*>(lBu + r * 64 + c) = make_uint2(u01, u23);
        }
        __syncthreads();
#pragma unroll
        for (int ks = 0; ks < 2; ++ks) {
            const int koff = ks * 32 + (lane >> 4) * 8;
            bf16x8 af[4], bg[4], bu[4];
#pragma unroll
            for (int mi = 0; mi < 4; ++mi)
                af[mi] = *reinterpret_cast<const bf16x8*>(lA + (wr * 64 + mi * 16 + (lane & 15)) * 64 + koff);
#pragma unroll
            for (int ni = 0; ni < 4; ++ni) {
                bg[ni] = *reinterpret_cast<const bf16x8*>(lBg + (wc * 64 + ni * 16 + (lane & 15)) * 64 + koff);
                bu[ni] = *reinterpret_cast<const bf16x8*>(lBu + (wc * 64 + ni * 16 + (lane & 15)) * 64 + koff);
            }
#pragma unroll
            for (int mi = 0; mi < 4; ++mi)
#pragma unroll
                for (int ni = 0; ni < 4; ++ni) {
                    accG[mi][ni] = __builtin_amdgcn_mfma_f32_16x16x32_bf16(af[mi], bg[ni], accG[mi][ni], 0, 0, 0);
                    accU[mi][ni] = __builtin_amdgcn_mfma_f32_16x16x32_bf16(af[mi], bu[ni], accU[mi][ni], 0, 0, 0);
                }
        }
    }
#pragma unroll
    for (int mi = 0; mi < 4; ++mi)
#pragma unroll
        for (int ni = 0; ni < 4; ++ni) {
            const int col = n0 + wc * 64 + ni * 16 + (lane & 15);
#pragma unroll
            for (int r = 0; r < 4; ++r) {
                const int row = m0 + wr * 64 + mi * 16 + (lane >> 4) * 4 + r;
                float gv = accG[mi][ni][r];
                float uv = accU[mi][ni][r];
                float hv = (gv / (1.0f + __expf(-gv))) * uv;
                H[(size_t)row * I_DIM + col] = f2bf(hv);
            }
        }
}

__global__ __launch_bounds__(256, 2)
void gemm_down_fb(const unsigned short* __restrict__ Hr,
                  const int* __restrict__ Wd, const float* __restrict__ Sd,
                  float* __restrict__ Out)
{
    __shared__ __align__(16) unsigned short lA[128 * 64];
    __shared__ __align__(16) unsigned short lB[128 * 64];
    const int MT = T_DIM / 128;
    const int bid = blockIdx.x;
    const int m0 = (bid % MT) * 128;
    const int n0 = (bid / MT) * 128;
    const int tid  = threadIdx.x;
    const int lane = tid & 63;
    const int wid  = tid >> 6;
    const int wr = wid >> 1, wc = wid & 1;
    f32x4 acc[4][4];
#pragma unroll
    for (int i = 0; i < 4; ++i)
#pragma unroll
        for (int j = 0; j < 4; ++j) acc[i][j] = (f32x4)0.0f;
    const int arow = lane >> 3;
    const int acol = (lane & 7) * 8;
    const int SStride = I_DIM / GRP;
    for (int k0 = 0; k0 < I_DIM; k0 += 64) {
        __syncthreads();
#pragma unroll
        for (int it = 0; it < 4; ++it) {
            int chunk = wid * 4 + it;
            const unsigned short* gp = Hr + (size_t)(m0 + chunk * 8 + arow) * I_DIM + k0 + acol;
            __builtin_amdgcn_global_load_lds((gmem_void*)gp, (lds_void*)(lA + chunk * 512), 16, 0, 0);
        }
        const int g = k0 >> 7;
#pragma unroll
        for (int i = 0; i < 8; ++i) {
            int linear = i * 1024 + tid * 4;
            int r = linear >> 6;
            int c = linear & 63;
            const int32x4 wd = *reinterpret_cast<const int32x4*>(Wd + (size_t)(n0 + r) * I_DIM + k0 + c);
            float sc = Sd[(size_t)(n0 + r) * SStride + g];
            unsigned int d01 = (unsigned int)f2bf((float)(wd.x - 8) * sc) | ((unsigned int)f2bf((float)(wd.y - 8) * sc) << 16);
            unsigned int d23 = (unsigned int)f2bf((float)(wd.z - 8) * sc) | ((unsigned int)f2bf((float)(wd.w - 8) * sc) << 16);
            *reinterpret_cast<uint2*>(lB + r * 64 + c) = make_uint2(d01, d23);
        }
        __syncthreads();
#pragma unroll
        for (int ks = 0; ks < 2; ++ks) {
            const int koff = ks * 32 + (lane >> 4) * 8;
            bf16x8 af[4], bfr[4];
#pragma unroll
            for (int mi = 0; mi < 4; ++mi)
                af[mi] = *reinterpret_cast<const bf16x8*>(lA + (wr * 64 + mi * 16 + (lane & 15)) * 64 + koff);
#pragma unroll
            for (int ni = 0; ni < 4; ++ni)
                bfr[ni] = *reinterpret_cast<const bf16x8*>(lB + (wc * 64 + ni * 16 + (lane & 15)) * 64 + koff);
#pragma unroll
            for (int mi = 0; mi < 4; ++mi)
#pragma unroll
                for (int ni = 0; ni < 4; ++ni)
                    acc[mi][ni] = __builtin_amdgcn_mfma_f32_16x16x32_bf16(af[mi], bfr[ni], acc[mi][ni], 0, 0, 0);
        }
    }
#pragma unroll
    for (int mi = 0; mi < 4; ++mi)
#pragma unroll
        for (int ni = 0; ni < 4; ++ni) {
            const int col = n0 + wc * 64 + ni * 16 + (lane & 15);
#pragma unroll
            for (int r = 0; r < 4; ++r) {
                const int row = m0 + wr * 64 + mi * 16 + (lane >> 4) * 4 + r;
                Out[(size_t)row * D_DIM + col] = acc[mi][ni][r];
            }
        }
}

extern "C" void kernel_launch(void* const* d_in, const int* in_sizes, int n_in,
                              void* d_out, int out_size, void* d_ws, size_t ws_size,
                              hipStream_t stream) {
    const float* x       = (const float*)d_in[0];
    const int*   wq_gate = (const int*)d_in[1];
    const float* s_gate  = (const float*)d_in[2];
    const int*   wq_up   = (const int*)d_in[3];
    const float* s_up    = (const float*)d_in[4];
    const int*   wq_down = (const int*)d_in[5];
    const float* s_down  = (const float*)d_in[6];
    float* out = (float*)d_out;

    const size_t XR_E = (size_t)T_DIM * D_DIM;      // 16.8M
    const size_t H_E  = (size_t)T_DIM * I_DIM;      // 50.3M
    const size_t W_E  = (size_t)I_DIM * D_DIM;      // 50.3M
    const size_t need = (XR_E + H_E + 2 * W_E) * sizeof(unsigned short);  // 335.5 MB

    unsigned short* xr = (unsigned short*)d_ws;
    unsigned short* h  = xr + XR_E;

    // 1) xr = hadamard(x) -> bf16
    {
        int ngroups = (int)(XR_E / 128);
        had_f32_to_bf16<<<dim3(ngroups / 4), dim3(256), 0, stream>>>(x, xr, ngroups);
    }

    if (ws_size >= need) {
        unsigned short* wgbf = h + H_E;
        unsigned short* wubf = wgbf + W_E;
        int total8 = (int)(W_E / 8);
        // 2) pre-dequant gate & up weights -> bf16
        dequant_w<<<dim3((total8 + 255) / 256), dim3(256), 0, stream>>>(wq_gate, s_gate, wgbf, D_DIM, total8);
        dequant_w<<<dim3((total8 + 255) / 256), dim3(256), 0, stream>>>(wq_up,   s_up,   wubf, D_DIM, total8);
        // 3) gate = xr @ Wg^T  (bf16, into h)
        gemm128x256<0><<<dim3((T_DIM / 128) * (I_DIM / 256)), dim3(512), 0, stream>>>(
            xr, wgbf, (void*)h, T_DIM, I_DIM, D_DIM);
        // 4) h = silu(gate) * (xr @ Wu^T)   (fused epilogue, in place over h)
        gemm128x256<1><<<dim3((T_DIM / 128) * (I_DIM / 256)), dim3(512), 0, stream>>>(
            xr, wubf, (void*)h, T_DIM, I_DIM, D_DIM);
        // 5) h = hadamard(h) in place
        {
            int ngroups = (int)(H_E / 128);
            had_bf16_inplace<<<dim3(ngroups / 4), dim3(256), 0, stream>>>(h, ngroups);
        }
        // 6) dequant down weights (reuse gate buffer)
        dequant_w<<<dim3((total8 + 255) / 256), dim3(256), 0, stream>>>(wq_down, s_down, wgbf, I_DIM, total8);
        // 7) out = h @ Wd^T  (f32)
        gemm128x256<2><<<dim3((T_DIM / 128) * (D_DIM / 256)), dim3(512), 0, stream>>>(
            h, wgbf, (void*)out, T_DIM, D_DIM, I_DIM);
    } else {
        // fallback: round-1 verified path (in-loop dequant)
        gemm_gateup_fb<<<dim3((T_DIM / 128) * (I_DIM / 128)), dim3(256), 0, stream>>>(
            xr, wq_gate, s_gate, wq_up, s_up, h);
        {
            int ngroups = (int)(H_E / 128);
            had_bf16_inplace<<<dim3(ngroups / 4), dim3(256), 0, stream>>>(h, ngroups);
        }
        gemm_down_fb<<<dim3((T_DIM / 128) * (D_DIM / 128)), dim3(256), 0, stream>>>(
            h, wq_down, s_down, out);
    }
}